// Round 2
// baseline (810.199 us; speedup 1.0000x reference)
//
#include <hip/hip_runtime.h>

#define BSZ   32768
#define INF   1024
#define UNITS 1024
#define NE    8

using bf16x8 = __attribute__((ext_vector_type(8))) __bf16;
using f32x4  = __attribute__((ext_vector_type(4))) float;

// async global -> LDS, 16B per lane; LDS dest is wave-uniform base + lane*16
#define GLD_LDS16(gp, lp)                                                        \
  __builtin_amdgcn_global_load_lds((__attribute__((address_space(1))) void*)(gp),\
                                   (__attribute__((address_space(3))) void*)(lp),\
                                   16, 0, 0)

// ---------------------------------------------------------------------------
// Prepass 1: alpha (E, IN, UNITS) f32  ->  alphaT (E, UNITS, IN) bf16
// ---------------------------------------------------------------------------
__global__ __launch_bounds__(256) void transpose_cvt(const float* __restrict__ a,
                                                     __bf16* __restrict__ at) {
  __shared__ float tile[32][33];
  const int e  = blockIdx.z;
  const int u0 = blockIdx.x * 32;
  const int i0 = blockIdx.y * 32;
  const float* src = a  + (size_t)e * (INF * UNITS);
  __bf16*      dst = at + (size_t)e * (INF * UNITS);
  const int tx = threadIdx.x & 31, ty = threadIdx.x >> 5;  // 32 x 8
#pragma unroll
  for (int r = 0; r < 32; r += 8)
    tile[ty + r][tx] = src[(size_t)(i0 + ty + r) * UNITS + (u0 + tx)];
  __syncthreads();
#pragma unroll
  for (int r = 0; r < 32; r += 8)
    dst[(size_t)(u0 + ty + r) * INF + (i0 + tx)] = (__bf16)tile[tx][ty + r];
}

// ---------------------------------------------------------------------------
// Prepass 2: x (B, IN) f32 -> xb (B, IN) bf16   (8 elements / thread)
// ---------------------------------------------------------------------------
__global__ __launch_bounds__(256) void cvt_x(const float* __restrict__ x,
                                             __bf16* __restrict__ xb) {
  const size_t i = ((size_t)blockIdx.x * 256 + threadIdx.x) * 8;
  f32x4 a = *(const f32x4*)(x + i);
  f32x4 b = *(const f32x4*)(x + i + 4);
  bf16x8 h;
  h[0] = (__bf16)a.x; h[1] = (__bf16)a.y; h[2] = (__bf16)a.z; h[3] = (__bf16)a.w;
  h[4] = (__bf16)b.x; h[5] = (__bf16)b.y; h[6] = (__bf16)b.z; h[7] = (__bf16)b.w;
  *(bf16x8*)(xb + i) = h;
}

// ---------------------------------------------------------------------------
// 256x256x(BK=64) 8-phase GEMM, fragment-pipelined depth 1, 1 barrier/phase.
//   Horner: after expert e, acc = (sum_{e'<=e} g_e' P_e') / g_e
//   final: out = g7 * acc + sum_e g[b,e]*beta[e,u]
// Phase p: STAGE(p) [; vmcnt(4) at p1/p3/p5/p7] ; ds-loads for phase p+1 ;
//          MFMA(p) on regs loaded at p-1 (compiler-counted lgkm) ; s_barrier.
// Slot map (lA / lB each 4 slots of 128x64):
//   reads(p):  p0 lA01 | p1 lA01 | p2 lA01+lB23 | p3 lB23+lA23 | p4 lA23
//              p5 lA23 | p6 lA23+lB01 | p7 lB01+lA01(next)
//   stages(p): p0 lA2(kt1) p1 lA3 | p2 lB0(ktn) p3 lB1 | p4 lA0(ktn) p5 lA1 |
//              p6 lB2(ktn1) p7 lB3
//   vmcnt(4) at p1/p3/p5/p7 drains the stage-pair issued 3 phases earlier;
//   every stage's first reader is >=1 phase after its drain point; every
//   stage-write slot is disjoint from all concurrently-in-flight reads.
// ---------------------------------------------------------------------------
__global__ __launch_bounds__(512, 2) void gemm_kernel(
    const __bf16* __restrict__ xb, const float* __restrict__ gate,
    const __bf16* __restrict__ aT, const float* __restrict__ beta,
    float* __restrict__ out) {
  __shared__ __align__(16) __bf16 lA[4][128 * 64];   // 64 KiB
  __shared__ __align__(16) __bf16 lB[4][128 * 64];   // 64 KiB
  __shared__ float lG[256 * NE];                     // 8 KiB

  const int t    = threadIdx.x;
  const int wave = t >> 6;
  const int lane = t & 63;
  const int wm   = wave >> 2;        // 0..1  M half
  const int wn   = wave & 3;         // 0..3  N quarter
  const int hB   = wn >> 1;          // which B half-slot this wave reads
  const int fm   = lane & 15;
  const int kq   = lane >> 4;        // 0..3
  const int fq   = kq * 4;           // C/D row-quad base
  const int sw   = fm & 7;           // read-side chunk swizzle (row&7 == fm&7)
  const int bR   = (wn & 1) * 64 + fm;

  // XCD-aware bijective swizzle (512 wgs % 8 == 0), bn-major logical order.
  const int li = (blockIdx.x & 7) * 64 + (blockIdx.x >> 3);
  const int bn = (li >> 7) * 256;
  const int bm = (li & 127) * 256;

  // stage gates (512 thr x f32x4 = 256 rows x 8)
  *(f32x4*)&lG[t * 4] = *(const f32x4*)&gate[(size_t)bm * NE + t * 4];

  // staging: per half-tile each wave issues 2 calls covering 16 rows.
  // global source chunk is (lane&7) ^ (row&7) so LDS[row][c^(row&7)] == g[row][c].
  const int stRow   = wave * 16 + (lane >> 3);
  const int stChunk = ((lane & 7) ^ (lane >> 3)) << 3;  // bf16 elems
  const __bf16* pA  = xb + (size_t)(bm + stRow) * INF + stChunk;
  const __bf16* pB  = aT + (size_t)(bn + stRow) * INF + stChunk;

#define STAGE_A(SLOT, KT, HF)                                                   \
  do {                                                                          \
    const __bf16* s_ = pA + (size_t)(HF) * (128 * INF) + (((KT) & 15) << 6);    \
    GLD_LDS16(s_, &lA[SLOT][(wave * 16) * 64]);                                 \
    GLD_LDS16(s_ + 8 * INF, &lA[SLOT][(wave * 16 + 8) * 64]);                   \
  } while (0)

#define STAGE_B(SLOT, KT, HF)                                                   \
  do {                                                                          \
    const __bf16* s_ = pB + ((size_t)((KT) >> 4) << 20) +                       \
                       (size_t)(HF) * (128 * INF) + (((KT) & 15) << 6);         \
    GLD_LDS16(s_, &lB[SLOT][(wave * 16) * 64]);                                 \
    GLD_LDS16(s_ + 8 * INF, &lB[SLOT][(wave * 16 + 8) * 64]);                   \
  } while (0)

#define LDAF(SLOT, ROW, C) \
  (*(const bf16x8*)&lA[SLOT][((ROW) << 6) + ((((C) ^ sw)) << 3)])
#define LDBF(SLOT, ROW, C) \
  (*(const bf16x8*)&lB[SLOT][((ROW) << 6) + ((((C) ^ sw)) << 3)])

#define LOAD_A_TO(DST, SLOT, Q)                                   \
  _Pragma("unroll") for (int mm = 0; mm < 2; ++mm) {              \
    DST[mm][0] = LDAF(SLOT, (Q) * 32 + mm * 16 + fm, kq);         \
    DST[mm][1] = LDAF(SLOT, (Q) * 32 + mm * 16 + fm, 4 + kq);     \
  }

#define LOAD_BH(DST, SLOT, KH)                                    \
  _Pragma("unroll") for (int n = 0; n < 4; ++n)                   \
    DST[n][KH] = LDBF(SLOT, bR + n * 16, (KH) * 4 + kq);

#define VMW(N) asm volatile("s_waitcnt vmcnt(" #N ")" ::: "memory")

#define BAR()                                  \
  do {                                         \
    __builtin_amdgcn_s_barrier();              \
    asm volatile("" ::: "memory");             \
  } while (0)

#define MFMA8(AQ, BQ, Q)                                                       \
  do {                                                                         \
    __builtin_amdgcn_s_setprio(1);                                             \
    _Pragma("unroll") for (int mm = 0; mm < 2; ++mm)                           \
    _Pragma("unroll") for (int n = 0; n < 4; ++n) {                            \
      acc[(Q) * 2 + mm][n] = __builtin_amdgcn_mfma_f32_16x16x32_bf16(          \
          AQ[mm][0], BQ[n][0], acc[(Q) * 2 + mm][n], 0, 0, 0);                 \
      acc[(Q) * 2 + mm][n] = __builtin_amdgcn_mfma_f32_16x16x32_bf16(          \
          AQ[mm][1], BQ[n][1], acc[(Q) * 2 + mm][n], 0, 0, 0);                 \
    }                                                                          \
    __builtin_amdgcn_s_setprio(0);                                             \
  } while (0)

#define RESCALE(E)                                                 \
  do {                                                             \
    _Pragma("unroll") for (int m = 0; m < 8; ++m)                  \
    _Pragma("unroll") for (int r = 0; r < 4; ++r) {                \
      const int rowL  = wm * 128 + m * 16 + fq + r;                \
      const float go  = lG[rowL * NE + (E)-1];                     \
      const float gn  = lG[rowL * NE + (E)];                       \
      const float ra  = go / gn;                                   \
      _Pragma("unroll") for (int n = 0; n < 4; ++n)                \
        acc[m][n][r] *= ra;                                        \
    }                                                              \
  } while (0)

  bf16x8 aq0[2][2], aq1[2][2], bq0[4][2], bq1[4][2];
  f32x4  acc[8][4] = {};

  // ---- prologue: B0,B1(kt0) A0,A1(kt0) B2,B3(kt1); keep B2,B3 in flight ----
  STAGE_B(0, 0, 0); STAGE_B(1, 0, 1);
  STAGE_A(0, 0, 0); STAGE_A(1, 0, 1);
  STAGE_B(2, 1, 0); STAGE_B(3, 1, 1);
  VMW(4);                                            // kt0 A+B landed
  asm volatile("s_waitcnt lgkmcnt(0)" ::: "memory"); // lG store drained
  BAR();
  // warm-up: regs for phase p0 (q0 of kt0 + full B kt0)
  LOAD_BH(bq0, hB, 0); LOAD_BH(bq0, hB, 1);
  LOAD_A_TO(aq0, wm, 0);

#pragma unroll 1
  for (int i = 0; i < 63; ++i) {
    if (i && !(i & 7)) RESCALE(i >> 3);  // expert boundary (8 iters/expert)
    const int kt1 = 2 * i + 1, ktn = 2 * i + 2, ktn1 = 2 * i + 3;
    STAGE_A(2, kt1, 0);          LOAD_A_TO(aq1, wm, 1);                            MFMA8(aq0, bq0, 0); BAR();
    STAGE_A(3, kt1, 1); VMW(4);  LOAD_A_TO(aq0, wm, 2);                            MFMA8(aq1, bq0, 1); BAR();
    STAGE_B(0, ktn, 0);          LOAD_A_TO(aq1, wm, 3);     LOAD_BH(bq1, 2+hB, 0); MFMA8(aq0, bq0, 2); BAR();
    STAGE_B(1, ktn, 1); VMW(4);  LOAD_BH(bq1, 2+hB, 1);     LOAD_A_TO(aq0, 2+wm, 0); MFMA8(aq1, bq0, 3); BAR();
    STAGE_A(0, ktn, 0);          LOAD_A_TO(aq1, 2+wm, 1);                          MFMA8(aq0, bq1, 0); BAR();
    STAGE_A(1, ktn, 1); VMW(4);  LOAD_A_TO(aq0, 2+wm, 2);                          MFMA8(aq1, bq1, 1); BAR();
    STAGE_B(2, ktn1, 0);         LOAD_A_TO(aq1, 2+wm, 3);   LOAD_BH(bq0, hB, 0);   MFMA8(aq0, bq1, 2); BAR();
    STAGE_B(3, ktn1, 1); VMW(4); LOAD_BH(bq0, hB, 1);       LOAD_A_TO(aq0, wm, 0); MFMA8(aq1, bq1, 3); BAR();
  }
  {  // ---- i = 63 peeled: kt0=126, kt1=127; no stages beyond kt127 ----
    STAGE_A(2, 127, 0);          LOAD_A_TO(aq1, wm, 1);                            MFMA8(aq0, bq0, 0); BAR();
    STAGE_A(3, 127, 1); VMW(4);  LOAD_A_TO(aq0, wm, 2);                            MFMA8(aq1, bq0, 1); BAR();
                                 LOAD_A_TO(aq1, wm, 3);     LOAD_BH(bq1, 2+hB, 0); MFMA8(aq0, bq0, 2); BAR();
    VMW(0);                      LOAD_BH(bq1, 2+hB, 1);     LOAD_A_TO(aq0, 2+wm, 0); MFMA8(aq1, bq0, 3); BAR();
                                 LOAD_A_TO(aq1, 2+wm, 1);                          MFMA8(aq0, bq1, 0); BAR();
                                 LOAD_A_TO(aq0, 2+wm, 2);                          MFMA8(aq1, bq1, 1); BAR();
                                 LOAD_A_TO(aq1, 2+wm, 3);                          MFMA8(aq0, bq1, 2); BAR();
                                                                                   MFMA8(aq1, bq1, 3);
  }

  // ---- epilogue: out = g7*acc + sum_e g[b,e]*beta[e,u] ----
  float bcol[4][NE];
#pragma unroll
  for (int n = 0; n < 4; ++n) {
    const int u = bn + wn * 64 + n * 16 + fm;
#pragma unroll
    for (int e2 = 0; e2 < NE; ++e2) bcol[n][e2] = beta[e2 * UNITS + u];
  }
#pragma unroll
  for (int m = 0; m < 8; ++m) {
#pragma unroll
    for (int r = 0; r < 4; ++r) {
      const int rowL = wm * 128 + m * 16 + fq + r;
      const int b    = bm + rowL;
      float g8[NE];
#pragma unroll
      for (int e2 = 0; e2 < NE; ++e2) g8[e2] = lG[rowL * NE + e2];
#pragma unroll
      for (int n = 0; n < 4; ++n) {
        float bias = 0.f;
#pragma unroll
        for (int e2 = 0; e2 < NE; ++e2) bias += g8[e2] * bcol[n][e2];
        const int u = bn + wn * 64 + n * 16 + fm;
        out[(size_t)b * UNITS + u] = g8[7] * acc[m][n][r] + bias;
      }
    }
  }
}

// ---------------------------------------------------------------------------
extern "C" void kernel_launch(void* const* d_in, const int* in_sizes, int n_in,
                              void* d_out, int out_size, void* d_ws, size_t ws_size,
                              hipStream_t stream) {
  const float* x     = (const float*)d_in[0];  // (B, IN)
  const float* gate  = (const float*)d_in[1];  // (B, E)
  const float* alpha = (const float*)d_in[2];  // (E, IN, UNITS)
  const float* beta  = (const float*)d_in[3];  // (E, UNITS)
  float* out         = (float*)d_out;          // (B, UNITS)
  __bf16* aT  = (__bf16*)d_ws;                                     // 16 MiB
  __bf16* xbp = (__bf16*)((char*)d_ws + (size_t)16 * 1024 * 1024); // 64 MiB

  transpose_cvt<<<dim3(UNITS / 32, INF / 32, NE), 256, 0, stream>>>(alpha, aT);
  cvt_x<<<dim3(BSZ * INF / (256 * 8)), 256, 0, stream>>>(x, xbp);
  gemm_kernel<<<dim3(512), 512, 0, stream>>>(xbp, gate, aT, beta, out);
}

// Round 3
// 805.177 us; speedup vs baseline: 1.0062x; 1.0062x over previous
//
#include <hip/hip_runtime.h>

#define BSZ   32768
#define INF   1024
#define UNITS 1024
#define NE    8

using bf16x8 = __attribute__((ext_vector_type(8))) __bf16;
using f32x4  = __attribute__((ext_vector_type(4))) float;

// async global -> LDS, 16B per lane; LDS dest is wave-uniform base + lane*16
#define GLD_LDS16(gp, lp)                                                        \
  __builtin_amdgcn_global_load_lds((__attribute__((address_space(1))) void*)(gp),\
                                   (__attribute__((address_space(3))) void*)(lp),\
                                   16, 0, 0)

// ---------------------------------------------------------------------------
// Prepass 1: alpha (E, IN, UNITS) f32 -> pk: B-fragment-major bf16 records.
// Record R = ((e*16+kt)*2 + kh)*64 + n16  (1024 B each, 16 MiB total):
//   record[lane l][j] = alpha[e][kt*64 + kh*32 + (l>>4)*8 + j][n16*16 + (l&15)]
// A wave's LOAD of record R via dwordx4 at (R*1024 + l*16) reproduces exactly
// the B-fragment the old LDS path delivered.
// ---------------------------------------------------------------------------
__global__ __launch_bounds__(256) void pack_b(const float* __restrict__ a,
                                              __bf16* __restrict__ pk) {
  __shared__ float ld[64][132];  // 64 k-rows x 128 u-cols (+pad)
  const int e  = blockIdx.z;   // 0..7
  const int kt = blockIdx.y;   // 0..15
  const int ub = blockIdx.x;   // 0..7 (u-block of 128)
  const float* src = a + (size_t)e * (INF * UNITS) + (size_t)(kt * 64) * UNITS + ub * 128;
  const int c = threadIdx.x & 127, r2 = threadIdx.x >> 7;  // 2 rows / pass
#pragma unroll 4
  for (int p = 0; p < 32; ++p)
    ld[p * 2 + r2][c] = src[(size_t)(p * 2 + r2) * UNITS + c];
  __syncthreads();
  const int l = threadIdx.x & 63, rl = threadIdx.x >> 6;
  const int kq_ = l >> 4, fm_ = l & 15;
  for (int rec = rl; rec < 16; rec += 4) {
    const int kh = rec >> 3, n16l = rec & 7;
    bf16x8 v;
#pragma unroll
    for (int j = 0; j < 8; ++j)
      v[j] = (__bf16)ld[kh * 32 + kq_ * 8 + j][n16l * 16 + fm_];
    const size_t R = (size_t)((e * 16 + kt) * 2 + kh) * 64 + ub * 8 + n16l;
    *(bf16x8*)(pk + R * 512 + l * 8) = v;
  }
}

// ---------------------------------------------------------------------------
// Prepass 2: x (B, IN) f32 -> xb (B, IN) bf16   (8 elements / thread)
// ---------------------------------------------------------------------------
__global__ __launch_bounds__(256) void cvt_x(const float* __restrict__ x,
                                             __bf16* __restrict__ xb) {
  const size_t i = ((size_t)blockIdx.x * 256 + threadIdx.x) * 8;
  f32x4 a = *(const f32x4*)(x + i);
  f32x4 b = *(const f32x4*)(x + i + 4);
  bf16x8 h;
  h[0] = (__bf16)a.x; h[1] = (__bf16)a.y; h[2] = (__bf16)a.z; h[3] = (__bf16)a.w;
  h[4] = (__bf16)b.x; h[5] = (__bf16)b.y; h[6] = (__bf16)b.z; h[7] = (__bf16)b.w;
  *(bf16x8*)(xb + i) = h;
}

// ---------------------------------------------------------------------------
// 256x256x(BK=64) GEMM, Horner gate folding. B-fragments load DIRECTLY from
// the L2-resident packed panel into registers (no LDS for B). A uses 8 LDS
// half-slots (4 K-tiles buffered); tile KT lives in slots (KT&3)*2 + {0,1}.
// Macro-iter j = 4 tiles = 16 phases; per phase: {4 A-ds_reads ; optional
// A-stage GLD + B-frag global loads ; barrier ; lgkm(0) ; 16 MFMA ; barrier}.
// Staging: ph0,1->T3(pair3) ph4,5->T4(pair0) ph8,9->T5(pair1) ph12,13->T6(pair2)
// (each pair restaged 1 phase after its last read, 11 phases before next read).
// Drain-before-read is via the compiler's dataflow vmcnt for each new bq set
// (issued AFTER the A-stage it must cover) + the phase barrier; no manual
// vmcnt in the loop. B dbuf: even tiles use bqA, odd use bqB, loaded in the
// first 2 phases of the 4-phases-earlier tile.
// ---------------------------------------------------------------------------
__global__ __launch_bounds__(512, 2) void gemm_kernel(
    const __bf16* __restrict__ xb, const float* __restrict__ gate,
    const __bf16* __restrict__ pk, const float* __restrict__ beta,
    float* __restrict__ out) {
  __shared__ __align__(16) __bf16 lA[8][128 * 64];   // 128 KiB
  __shared__ float lG[256 * NE];                     // 8 KiB

  const int t    = threadIdx.x;
  const int wave = t >> 6;
  const int lane = t & 63;
  const int wm   = wave >> 2;        // 0..1  M half
  const int wn   = wave & 3;         // 0..3  N quarter
  const int hB   = wn >> 1;          // B col-half (128)
  const int fm   = lane & 15;
  const int kq   = lane >> 4;        // 0..3
  const int fq   = kq * 4;           // C/D row-quad base
  const int sw   = fm & 7;           // read-side chunk swizzle
  const int lane8 = lane * 8;

  // XCD-aware bijective swizzle (512 wgs % 8 == 0), bn-major logical order.
  const int li = (blockIdx.x & 7) * 64 + (blockIdx.x >> 3);
  const int bn = (li >> 7) * 256;
  const int bm = (li & 127) * 256;
  const int n16b = (bn >> 4) + hB * 8 + (wn & 1) * 4;  // record col-base

  // stage gates (512 thr x f32x4 = 256 rows x 8)
  *(f32x4*)&lG[t * 4] = *(const f32x4*)&gate[(size_t)bm * NE + t * 4];

  // A staging: global source chunk pre-swizzled: (lane&7)^(row&7).
  const int stRow   = wave * 16 + (lane >> 3);
  const int stChunk = ((lane & 7) ^ (lane >> 3)) << 3;
  const __bf16* pA  = xb + (size_t)(bm + stRow) * INF + stChunk;

#define STAGE_A(SLOT, KT, HF)                                                   \
  do {                                                                          \
    const __bf16* s_ = pA + (size_t)(HF) * (128 * INF) + (((KT) & 15) << 6);    \
    GLD_LDS16(s_, &lA[SLOT][(wave * 16) * 64]);                                 \
    GLD_LDS16(s_ + 8 * INF, &lA[SLOT][(wave * 16 + 8) * 64]);                   \
  } while (0)

#define LDAF(SLOT, ROW, C) \
  (*(const bf16x8*)&lA[SLOT][((ROW) << 6) + ((((C) ^ sw)) << 3)])

#define DSA(PAIR, Q)                                                        \
  _Pragma("unroll") for (int mm = 0; mm < 2; ++mm) {                        \
    aq[mm][0] = LDAF((PAIR) * 2 + wm, (Q) * 32 + mm * 16 + fm, kq);         \
    aq[mm][1] = LDAF((PAIR) * 2 + wm, (Q) * 32 + mm * 16 + fm, 4 + kq);     \
  }

#define LDB(DST, KT, KH)                                                    \
  _Pragma("unroll") for (int n = 0; n < 4; ++n)                             \
    DST[n][KH] = *(const bf16x8*)(pk +                                      \
        ((size_t)((KT) * 2 + (KH)) * 64 + n16b + n) * 512 + lane8);

#define MF(BQ, Q)                                                              \
  do {                                                                         \
    __builtin_amdgcn_s_barrier();                                              \
    asm volatile("s_waitcnt lgkmcnt(0)" ::: "memory");                         \
    __builtin_amdgcn_s_setprio(1);                                             \
    _Pragma("unroll") for (int mm = 0; mm < 2; ++mm)                           \
    _Pragma("unroll") for (int n = 0; n < 4; ++n) {                            \
      acc[(Q) * 2 + mm][n] = __builtin_amdgcn_mfma_f32_16x16x32_bf16(          \
          aq[mm][0], BQ[n][0], acc[(Q) * 2 + mm][n], 0, 0, 0);                 \
      acc[(Q) * 2 + mm][n] = __builtin_amdgcn_mfma_f32_16x16x32_bf16(          \
          aq[mm][1], BQ[n][1], acc[(Q) * 2 + mm][n], 0, 0, 0);                 \
    }                                                                          \
    __builtin_amdgcn_s_setprio(0);                                             \
    __builtin_amdgcn_s_barrier();                                              \
    asm volatile("" ::: "memory");                                             \
  } while (0)

#define RESCALE(E)                                                 \
  do {                                                             \
    _Pragma("unroll") for (int m = 0; m < 8; ++m)                  \
    _Pragma("unroll") for (int r = 0; r < 4; ++r) {                \
      const int rowL  = wm * 128 + m * 16 + fq + r;                \
      const float go  = lG[rowL * NE + (E)-1];                     \
      const float gn  = lG[rowL * NE + (E)];                       \
      const float ra  = go / gn;                                   \
      _Pragma("unroll") for (int n = 0; n < 4; ++n)                \
        acc[m][n][r] *= ra;                                        \
    }                                                              \
  } while (0)

  bf16x8 aq[2][2], bqA[4][2], bqB[4][2];
  f32x4  acc[8][4] = {};

  // ---- prologue: stage A tiles 0,1,2 (T3 staged at j0-ph0); load bq(T0) ----
  STAGE_A(0, 0, 0); STAGE_A(1, 0, 1);
  STAGE_A(2, 1, 0); STAGE_A(3, 1, 1);
  STAGE_A(4, 2, 0); STAGE_A(5, 2, 1);
  asm volatile("" ::: "memory");
  LDB(bqA, 0, 0); LDB(bqA, 0, 1);
  asm volatile("" ::: "memory");
  asm volatile("s_waitcnt vmcnt(16)" ::: "memory");  // T0 (oldest 4) landed
  asm volatile("s_waitcnt lgkmcnt(0)" ::: "memory"); // lG visible
  __builtin_amdgcn_s_barrier();
  asm volatile("" ::: "memory");

#pragma unroll 1
  for (int j = 0; j < 31; ++j) {
    if (j && !(j & 3)) RESCALE(j >> 2);  // expert boundary (4 macro-iters each)
    const int T1 = 4 * j + 1, T2 = 4 * j + 2, T3 = 4 * j + 3;
    const int T4 = 4 * j + 4, T5 = 4 * j + 5, T6 = 4 * j + 6;
    // tile T0 (pair0, bqA)
    DSA(0, 0); STAGE_A(6, T3, 0); LDB(bqB, T1, 0); MF(bqA, 0);
    DSA(0, 1); STAGE_A(7, T3, 1); LDB(bqB, T1, 1); MF(bqA, 1);
    DSA(0, 2);                                      MF(bqA, 2);
    DSA(0, 3);                                      MF(bqA, 3);
    // tile T1 (pair1, bqB)
    DSA(1, 0); STAGE_A(0, T4, 0); LDB(bqA, T2, 0); MF(bqB, 0);
    DSA(1, 1); STAGE_A(1, T4, 1); LDB(bqA, T2, 1); MF(bqB, 1);
    DSA(1, 2);                                      MF(bqB, 2);
    DSA(1, 3);                                      MF(bqB, 3);
    // tile T2 (pair2, bqA)
    DSA(2, 0); STAGE_A(2, T5, 0); LDB(bqB, T3, 0); MF(bqA, 0);
    DSA(2, 1); STAGE_A(3, T5, 1); LDB(bqB, T3, 1); MF(bqA, 1);
    DSA(2, 2);                                      MF(bqA, 2);
    DSA(2, 3);                                      MF(bqA, 3);
    // tile T3 (pair3, bqB)
    DSA(3, 0); STAGE_A(4, T6, 0); LDB(bqA, T4, 0); MF(bqB, 0);
    DSA(3, 1); STAGE_A(5, T6, 1); LDB(bqA, T4, 1); MF(bqB, 1);
    DSA(3, 2);                                      MF(bqB, 2);
    DSA(3, 3);                                      MF(bqB, 3);
  }
  {  // ---- j = 31 peeled (tiles 124..127): no stages/loads past KT=127 ----
    DSA(0, 0); STAGE_A(6, 127, 0); LDB(bqB, 125, 0); MF(bqA, 0);
    DSA(0, 1); STAGE_A(7, 127, 1); LDB(bqB, 125, 1); MF(bqA, 1);
    DSA(0, 2);                                        MF(bqA, 2);
    DSA(0, 3);                                        MF(bqA, 3);
    DSA(1, 0);                     LDB(bqA, 126, 0);  MF(bqB, 0);
    DSA(1, 1);                     LDB(bqA, 126, 1);  MF(bqB, 1);
    DSA(1, 2);                                        MF(bqB, 2);
    DSA(1, 3);                                        MF(bqB, 3);
    DSA(2, 0);                     LDB(bqB, 127, 0);  MF(bqA, 0);
    DSA(2, 1);                     LDB(bqB, 127, 1);  MF(bqA, 1);
    DSA(2, 2);                                        MF(bqA, 2);
    DSA(2, 3);                                        MF(bqA, 3);
    DSA(3, 0);                                        MF(bqB, 0);
    DSA(3, 1);                                        MF(bqB, 1);
    DSA(3, 2);                                        MF(bqB, 2);
    DSA(3, 3);                                        MF(bqB, 3);
  }

  // ---- epilogue: out = g7*acc + sum_e g[b,e]*beta[e,u] ----
  float bcol[4][NE];
#pragma unroll
  for (int n = 0; n < 4; ++n) {
    const int u = bn + wn * 64 + n * 16 + fm;
#pragma unroll
    for (int e2 = 0; e2 < NE; ++e2) bcol[n][e2] = beta[e2 * UNITS + u];
  }
#pragma unroll
  for (int m = 0; m < 8; ++m) {
#pragma unroll
    for (int r = 0; r < 4; ++r) {
      const int rowL = wm * 128 + m * 16 + fq + r;
      const int b    = bm + rowL;
      float g8[NE];
#pragma unroll
      for (int e2 = 0; e2 < NE; ++e2) g8[e2] = lG[rowL * NE + e2];
#pragma unroll
      for (int n = 0; n < 4; ++n) {
        float bias = 0.f;
#pragma unroll
        for (int e2 = 0; e2 < NE; ++e2) bias += g8[e2] * bcol[n][e2];
        const int u = bn + wn * 64 + n * 16 + fm;
        out[(size_t)b * UNITS + u] = g8[7] * acc[m][n][r] + bias;
      }
    }
  }
}

// ---------------------------------------------------------------------------
extern "C" void kernel_launch(void* const* d_in, const int* in_sizes, int n_in,
                              void* d_out, int out_size, void* d_ws, size_t ws_size,
                              hipStream_t stream) {
  const float* x     = (const float*)d_in[0];  // (B, IN)
  const float* gate  = (const float*)d_in[1];  // (B, E)
  const float* alpha = (const float*)d_in[2];  // (E, IN, UNITS)
  const float* beta  = (const float*)d_in[3];  // (E, UNITS)
  float* out         = (float*)d_out;          // (B, UNITS)
  __bf16* pk  = (__bf16*)d_ws;                                     // 16 MiB
  __bf16* xbp = (__bf16*)((char*)d_ws + (size_t)16 * 1024 * 1024); // 64 MiB

  pack_b<<<dim3(8, 16, NE), 256, 0, stream>>>(alpha, pk);
  cvt_x<<<dim3(BSZ * INF / (256 * 8)), 256, 0, stream>>>(x, xbp);
  gemm_kernel<<<dim3(512), 512, 0, stream>>>(xbp, gate, pk, beta, out);
}